// Round 11
// baseline (77.240 us; speedup 1.0000x reference)
//
#include <hip/hip_runtime.h>

// Problem constants (match reference setup)
#define BB     4
#define NW     128
#define HG     512
#define WG     512
#define EDIM   64
#define HIDDEN 768
#define CTS    132

typedef float f4 __attribute__((ext_vector_type(4)));

// d_ws layout (bytes):
#define WS_CTABT  0         // [4][64][132] f32  = 135,168
#define WS_CNT    135168    // [64] u32          = 256
#define WS_SUBCNT 135424    // [64][4] u32       = 1,024
#define WS_ENTX   136448    // [64][128] u32     = 32,768
#define WS_ENTY   169216    // [64][128] u32     = 32,768
#define WS_SUB    201984    // [64][4][128] u8   = 32,768

// ---------------------------------------------------------------------------
// Prep: blocks 0..131   -> ctabT[b][e][n] (LDS-tiled GEMM, R6 pattern)
//       blocks 132..195 -> per-(b, 32-row tile) box lists + 8-row sub-lists
// ---------------------------------------------------------------------------
__global__ __launch_bounds__(256) void prep_kernel(
    const float* __restrict__ bbox,
    const float* __restrict__ emb,
    const float* __restrict__ proj,
    const int*   __restrict__ ids,
    const int*   __restrict__ stride_p,
    float*         __restrict__ ctabT,
    unsigned*      __restrict__ cnt_g,
    unsigned*      __restrict__ subcnt_g,
    unsigned*      __restrict__ entx_g,
    unsigned*      __restrict__ enty_g,
    unsigned char* __restrict__ sub_g)
{
    const int t  = threadIdx.x;
    const int bx = blockIdx.x;

    if (bx < 132) {
        __shared__ float proj_s[64][68];
        __shared__ float emb_s[4][68];

        const int b = bx / 33, ng = bx % 33;
        const int e = t & 63, r = t >> 6;
        const int n = ng * 4 + r;              // 0..131
        const bool valid = (n <= NW);
        const int id = (!valid || n == 0) ? 0 : ids[b * NW + n - 1];
        const float* erow = emb + (size_t)id * HIDDEN;

        float acc = 0.f;
        for (int kt = 0; kt < HIDDEN; kt += 64) {
            if (e < 16)
                *(f4*)&emb_s[r][e * 4] = ((const f4*)(erow + kt))[e];
            #pragma unroll
            for (int q = t; q < 1024; q += 256) {
                const int pr = q >> 4, pc = q & 15;
                *(f4*)&proj_s[pr][pc * 4] =
                    ((const f4*)(proj + (size_t)pr * HIDDEN + kt))[pc];
            }
            __syncthreads();
            #pragma unroll
            for (int k4 = 0; k4 < 16; ++k4) {
                f4 a = *(const f4*)&emb_s[r][k4 * 4];
                f4 p = *(const f4*)&proj_s[e][k4 * 4];
                acc += a.x * p.x + a.y * p.y + a.z * p.z + a.w * p.w;
            }
            __syncthreads();
        }
        if (valid) ctabT[((size_t)(b * EDIM + e)) * CTS + n] = acc;
        return;
    }

    // ---- list builder: one block per (b, 32-row tile) ----
    const int wb  = bx - 132;              // 0..63
    const int b   = wb >> 4, ht = wb & 15;
    const int rlo = ht * 32, rhi = rlo + 32;

    __shared__ unsigned entx[NW], enty[NW];
    __shared__ unsigned char sub[4][NW];
    __shared__ int subcnt[4];
    __shared__ int cnt;
    if (t == 0) cnt = 0;
    if (t < 4)  subcnt[t] = 0;
    __syncthreads();

    if (t < NW) {
        const float s = (float)stride_p[0];
        float4 bv = ((const float4*)bbox)[b * NW + t];
        int w0 = (int)rintf(bv.x / s), h0 = (int)rintf(bv.y / s);
        int w1 = (int)rintf(bv.z / s), h1 = (int)rintf(bv.w / s);
        if (h1 > rlo && h0 < rhi && w1 > w0 && h1 > h0) {
            int i = atomicAdd(&cnt, 1);
            entx[i] = (unsigned)w0 | ((unsigned)w1 << 10) | ((unsigned)(t + 1) << 20);
            enty[i] = (unsigned)h0 | ((unsigned)h1 << 16);
        }
    }
    __syncthreads();

    const int nc = cnt;
    if (t < nc) {
        const unsigned ey = enty[t];
        const int h0 = (int)(ey & 0xFFFFu), h1 = (int)(ey >> 16);
        #pragma unroll
        for (int st = 0; st < 4; ++st) {
            const int srl = rlo + st * 8;
            if (h1 > srl && h0 < srl + 8) {
                int k = atomicAdd(&subcnt[st], 1);
                sub[st][k] = (unsigned char)t;
            }
        }
    }
    __syncthreads();

    if (t < nc) {
        entx_g[wb * NW + t] = entx[t];
        enty_g[wb * NW + t] = enty[t];
    }
    if (t == 0) cnt_g[wb] = (unsigned)nc;
    if (t < 4) {
        subcnt_g[wb * 4 + t] = (unsigned)subcnt[t];
        for (int k = 0; k < subcnt[t]; ++k)
            sub_g[((size_t)wb * 4 + t) * NW + k] = sub[t][k];
    }
}

// ---------------------------------------------------------------------------
// Paint: 1024 blocks = 8 XCDs x 128 (bijective swizzle). lin = b|e4|ht.
// FOUR e-planes per block, 32-row tile; wave = one 8-row sub-tile (ns is
// wave-constant). Setup ~1.3 KB from L2, then pure winner+gather+store.
// Plain f4 stores (NT bypasses L2 write-combining: R8 = -10.5 us).
// ---------------------------------------------------------------------------
__global__ __launch_bounds__(256) void paint_kernel(
    const float*         __restrict__ ctabT,
    const unsigned*      __restrict__ cnt_g,
    const unsigned*      __restrict__ subcnt_g,
    const unsigned*      __restrict__ entx_g,
    const unsigned*      __restrict__ enty_g,
    const unsigned char* __restrict__ sub_g,
    float*               __restrict__ out)
{
    const int t = threadIdx.x;
    const int lin = ((blockIdx.x & 7) << 7) | (blockIdx.x >> 3);   // 1024
    const int b  = lin >> 8;
    const int e0 = ((lin >> 4) & 15) * 4;
    const int ht = lin & 15;
    const int grp = b * 16 + ht;
    const int rlo = ht * 32;

    __shared__ unsigned entx[NW], enty[NW];
    __shared__ unsigned char sub[4][NW];
    __shared__ int   subcnt[4];
    __shared__ float col[4][CTS];

    const int nc = (int)cnt_g[grp];
    if (t < 4)  subcnt[t] = (int)subcnt_g[grp * 4 + t];
    if (t < NW) {
        entx[t] = entx_g[grp * NW + t];
        enty[t] = enty_g[grp * NW + t];
    }
    if (t < 128)
        ((unsigned*)sub)[t] = ((const unsigned*)(sub_g + (size_t)grp * 512))[t];
    __syncthreads();

    for (int idx = t; idx < (nc + 1) * 4; idx += 256) {
        const int i = idx >> 2, p = idx & 3;
        const int n = (i == nc) ? 0 : (int)(entx[i] >> 20);
        col[p][n] = ctabT[((size_t)(b * EDIM + e0 + p)) * CTS + n];
    }
    __syncthreads();

    const int wv = t >> 6, l = t & 63;
    const int p0 = 4 * l, p1 = 256 + 4 * l;
    const size_t PLq = (size_t)HG * WG / 4;             // plane stride in f4
    float* ob0 = out + ((size_t)(b * EDIM + e0)) * HG * WG;

    const int ns = subcnt[wv];                          // wave = one sub-tile
    f4 bg[4];
    #pragma unroll
    for (int p = 0; p < 4; ++p) {
        const float c = col[p][0];
        bg[p] = (f4){c, c, c, c};
    }

    for (int rr = 0; rr < 8; ++rr) {
        const int row = rlo + wv * 8 + rr;              // wave-uniform
        f4* orow = (f4*)(ob0 + (size_t)row * WG);

        if (ns == 0) {                                  // bg fast path
            #pragma unroll
            for (int p = 0; p < 4; ++p) {
                orow[p * PLq + l]      = bg[p];
                orow[p * PLq + 64 + l] = bg[p];
            }
            continue;
        }

        int wn0 = 0, wn1 = 0, wn2 = 0, wn3 = 0;
        int wn4 = 0, wn5 = 0, wn6 = 0, wn7 = 0;
        for (int k = 0; k < ns; ++k) {
            const int i = sub[wv][k];
            const unsigned ey = enty[i];                // broadcast LDS read
            const int h0 = (int)(ey & 0xFFFFu), h1 = (int)(ey >> 16);
            if (row >= h0 && row < h1) {                // wave-uniform branch
                const unsigned ex = entx[i];
                const int w0 = (int)(ex & 1023u);
                const int w1 = (int)((ex >> 10) & 1023u);
                const int pr = (int)(ex >> 20);
                if (p0     >= w0 && p0     < w1 && pr > wn0) wn0 = pr;
                if (p0 + 1 >= w0 && p0 + 1 < w1 && pr > wn1) wn1 = pr;
                if (p0 + 2 >= w0 && p0 + 2 < w1 && pr > wn2) wn2 = pr;
                if (p0 + 3 >= w0 && p0 + 3 < w1 && pr > wn3) wn3 = pr;
                if (p1     >= w0 && p1     < w1 && pr > wn4) wn4 = pr;
                if (p1 + 1 >= w0 && p1 + 1 < w1 && pr > wn5) wn5 = pr;
                if (p1 + 2 >= w0 && p1 + 2 < w1 && pr > wn6) wn6 = pr;
                if (p1 + 3 >= w0 && p1 + 3 < w1 && pr > wn7) wn7 = pr;
            }
        }
        #pragma unroll
        for (int p = 0; p < 4; ++p) {
            f4 u0, u1;
            u0.x = col[p][wn0]; u0.y = col[p][wn1];
            u0.z = col[p][wn2]; u0.w = col[p][wn3];
            u1.x = col[p][wn4]; u1.y = col[p][wn5];
            u1.z = col[p][wn6]; u1.w = col[p][wn7];
            orow[p * PLq + l]      = u0;
            orow[p * PLq + 64 + l] = u1;
        }
    }
}

// ---------------------------------------------------------------------------
extern "C" void kernel_launch(void* const* d_in, const int* in_sizes, int n_in,
                              void* d_out, int out_size, void* d_ws, size_t ws_size,
                              hipStream_t stream)
{
    // inputs: 0 img (unused), 1 bbox, 2 emb_weight, 3 proj_weight,
    //         4 input_ids, 5 stride
    const float* bbox = (const float*)d_in[1];
    const float* emb  = (const float*)d_in[2];
    const float* proj = (const float*)d_in[3];
    const int*   ids  = (const int*)d_in[4];
    const int*   strd = (const int*)d_in[5];

    float* out = (float*)d_out;
    char*  ws  = (char*)d_ws;
    float*         ctabT  = (float*)(ws + WS_CTABT);
    unsigned*      cntg   = (unsigned*)(ws + WS_CNT);
    unsigned*      subcg  = (unsigned*)(ws + WS_SUBCNT);
    unsigned*      entxg  = (unsigned*)(ws + WS_ENTX);
    unsigned*      entyg  = (unsigned*)(ws + WS_ENTY);
    unsigned char* subg   = (unsigned char*)(ws + WS_SUB);

    prep_kernel<<<196, 256, 0, stream>>>(
        bbox, emb, proj, ids, strd, ctabT, cntg, subcg, entxg, entyg, subg);

    paint_kernel<<<1024, 256, 0, stream>>>(
        ctabT, cntg, subcg, entxg, entyg, subg, out);
}

// Round 12
// 75.726 us; speedup vs baseline: 1.0200x; 1.0200x over previous
//
#include <hip/hip_runtime.h>

// Problem constants (match reference setup)
#define BB     4
#define NW     128
#define HG     512
#define WG     512
#define EDIM   64
#define HIDDEN 768
#define CTS    132

typedef float f4 __attribute__((ext_vector_type(4)));

// d_ws layout (bytes):
//   ctabT : [BB][EDIM][CTS] f32  @ 0        (135,168 B)
//   winner: [BB][HG][WG] u8      @ 139,264  (1,048,576 B)
#define WS_CTABT  0
#define WS_WINNER 139264

// ---------------------------------------------------------------------------
// Prep: blocks 0..131   -> ctabT[b][e][n]  (LDS-tiled GEMM, verified R6)
//       blocks 132..387 -> winner map u8   (per-(b,8-row) raster, verified R2)
// ---------------------------------------------------------------------------
__global__ __launch_bounds__(256) void prep_kernel(
    const float* __restrict__ bbox,
    const float* __restrict__ emb,
    const float* __restrict__ proj,
    const int*   __restrict__ ids,
    const int*   __restrict__ stride_p,
    float*         __restrict__ ctabT,
    unsigned char* __restrict__ winner)
{
    const int t  = threadIdx.x;
    const int bx = blockIdx.x;

    if (bx < 132) {
        __shared__ float proj_s[64][68];
        __shared__ float emb_s[4][68];

        const int b = bx / 33, ng = bx % 33;
        const int e = t & 63, r = t >> 6;
        const int n = ng * 4 + r;              // 0..131
        const bool valid = (n <= NW);
        const int id = (!valid || n == 0) ? 0 : ids[b * NW + n - 1];
        const float* erow = emb + (size_t)id * HIDDEN;

        float acc = 0.f;
        for (int kt = 0; kt < HIDDEN; kt += 64) {
            if (e < 16)
                *(f4*)&emb_s[r][e * 4] = ((const f4*)(erow + kt))[e];
            #pragma unroll
            for (int q = t; q < 1024; q += 256) {
                const int pr = q >> 4, pc = q & 15;
                *(f4*)&proj_s[pr][pc * 4] =
                    ((const f4*)(proj + (size_t)pr * HIDDEN + kt))[pc];
            }
            __syncthreads();
            #pragma unroll
            for (int k4 = 0; k4 < 16; ++k4) {
                f4 a = *(const f4*)&emb_s[r][k4 * 4];
                f4 p = *(const f4*)&proj_s[e][k4 * 4];
                acc += a.x * p.x + a.y * p.y + a.z * p.z + a.w * p.w;
            }
            __syncthreads();
        }
        if (valid) ctabT[((size_t)(b * EDIM + e)) * CTS + n] = acc;
        return;
    }

    // ---- winner raster: one block per (b, 8-row tile) ----
    const int wb    = bx - 132;            // 0..255
    const int b     = wb >> 6;
    const int hbase = (wb & 63) * 8;
    const float s = (float)stride_p[0];

    __shared__ int fw0[NW], fw1[NW], fh0[NW], fh1[NW], fpr[NW];
    __shared__ int cnt;
    if (t == 0) cnt = 0;
    __syncthreads();

    if (t < NW) {
        float4 bv = ((const float4*)bbox)[b * NW + t];
        int w0 = (int)rintf(bv.x / s);
        int h0 = (int)rintf(bv.y / s);
        int w1 = (int)rintf(bv.z / s);
        int h1 = (int)rintf(bv.w / s);
        if (h1 > hbase && h0 < hbase + 8) {
            int i = atomicAdd(&cnt, 1);
            fw0[i] = w0; fw1[i] = w1; fh0[i] = h0; fh1[i] = h1; fpr[i] = t + 1;
        }
    }
    __syncthreads();

    const int nc  = cnt;
    const int q   = t & 127;
    const int w0p = q * 4;
    for (int rr = 0; rr < 4; ++rr) {
        const int row = hbase + rr * 2 + (t >> 7);
        int wn0 = 0, wn1 = 0, wn2 = 0, wn3 = 0;
        for (int i = 0; i < nc; ++i) {
            if (row >= fh0[i] && row < fh1[i]) {
                int a = fw0[i], z = fw1[i], p = fpr[i];
                if (w0p     >= a && w0p     < z) wn0 = max(wn0, p);
                if (w0p + 1 >= a && w0p + 1 < z) wn1 = max(wn1, p);
                if (w0p + 2 >= a && w0p + 2 < z) wn2 = max(wn2, p);
                if (w0p + 3 >= a && w0p + 3 < z) wn3 = max(wn3, p);
            }
        }
        uchar4 u;
        u.x = (unsigned char)wn0; u.y = (unsigned char)wn1;
        u.z = (unsigned char)wn2; u.w = (unsigned char)wn3;
        *(uchar4*)(winner + ((size_t)(b * HG + row)) * WG + w0p) = u;
    }
}

// ---------------------------------------------------------------------------
// Paint: fill-mimic sliding-window sweep. 2048 blocks x 256 threads, each
// thread grid-strides over output quads in ADDRESS ORDER — at any instant
// the whole grid writes inside one sliding ~8 MB window (DRAM page local,
// like the 6.9 TB/s rocclr fill). Winner uchar4 + 4-float ctab gather both
// come from L2 (1 MB + 132 KB working set). Plain f4 stores (NT hurts: R8).
// ---------------------------------------------------------------------------
#define PAINT_BLOCKS 2048
__global__ __launch_bounds__(256) void paint_kernel(
    const float*  __restrict__ ctabT,
    const uchar4* __restrict__ winner4,   // [BB*HG*WG/4]
    f4*           __restrict__ out4)      // [BB*EDIM*HG*WG/4]
{
    int g = blockIdx.x * 256 + threadIdx.x;          // output quad index
    #pragma unroll 4
    for (int it = 0; it < 32; ++it, g += PAINT_BLOCKS * 256) {
        const int b   = g >> 22;                      // 4.19M quads per batch
        const int e   = (g >> 16) & 63;               // 65536 quads per plane
        const int rw  = g & 65535;                    // row*128 + wq
        uchar4 wn = winner4[(b << 16) + rw];          // [b][row][wq]
        const float* cb = ctabT + ((size_t)((b << 6) + e)) * CTS;
        f4 v;
        v.x = cb[wn.x]; v.y = cb[wn.y]; v.z = cb[wn.z]; v.w = cb[wn.w];
        out4[g] = v;
    }
}

// ---------------------------------------------------------------------------
extern "C" void kernel_launch(void* const* d_in, const int* in_sizes, int n_in,
                              void* d_out, int out_size, void* d_ws, size_t ws_size,
                              hipStream_t stream)
{
    // inputs: 0 img (unused), 1 bbox, 2 emb_weight, 3 proj_weight,
    //         4 input_ids, 5 stride
    const float* bbox = (const float*)d_in[1];
    const float* emb  = (const float*)d_in[2];
    const float* proj = (const float*)d_in[3];
    const int*   ids  = (const int*)d_in[4];
    const int*   strd = (const int*)d_in[5];

    float* out = (float*)d_out;
    char*  ws  = (char*)d_ws;
    float*         ctabT  = (float*)(ws + WS_CTABT);
    unsigned char* winner = (unsigned char*)(ws + WS_WINNER);

    prep_kernel<<<388, 256, 0, stream>>>(
        bbox, emb, proj, ids, strd, ctabT, winner);

    paint_kernel<<<PAINT_BLOCKS, 256, 0, stream>>>(
        ctabT, (const uchar4*)winner, (f4*)out);
}